// Round 1
// baseline (628.911 us; speedup 1.0000x reference)
//
#include <hip/hip_runtime.h>
#include <hip/hip_bf16.h>

#define L 4800
#define CH 256
#define KS 768       // split-K: [hi, hi, lo] x [hi, lo, hi]
#define NB 2
#define TT 38        // ceil(4800/128)

typedef short short8 __attribute__((ext_vector_type(8)));
typedef float f32x4 __attribute__((ext_vector_type(4)));

__device__ __forceinline__ unsigned short f2bf(float f) {
    unsigned u = __float_as_uint(f);
    unsigned r = (u + 0x7FFF + ((u >> 16) & 1)) >> 16;   // RNE
    return (unsigned short)r;
}
__device__ __forceinline__ float bf2f(unsigned short h) {
    return __uint_as_float(((unsigned)h) << 16);
}

// ---- K0: zero the atomic-accumulated stats ----
__global__ void init_stats(float* rowsum, float* colsum, unsigned* colmax) {
    int i = blockIdx.x * 256 + threadIdx.x;
    if (i < NB * L) { rowsum[i] = 0.f; colsum[i] = 0.f; colmax[i] = 0u; }
}

// ---- K1: fp32 -> bf16 hi/lo split matrices ----
__global__ void convert_kernel(const float* __restrict__ f0, const float* __restrict__ f1,
                               short* __restrict__ A, short* __restrict__ B) {
    int idx = blockIdx.x * 256 + threadIdx.x;
    if (idx >= NB * L * CH) return;
    int k = idx % CH;
    int r = (idx / CH) % L;
    int n = idx / (CH * L);
    long base = ((long)(n * L + r)) * KS;
    {
        float f = f0[idx];
        unsigned short h = f2bf(f);
        unsigned short lo = f2bf(f - bf2f(h));
        A[base + k]          = (short)h;
        A[base + CH + k]     = (short)h;
        A[base + 2 * CH + k] = (short)lo;
    }
    {
        float f = f1[idx];
        unsigned short h = f2bf(f);
        unsigned short lo = f2bf(f - bf2f(h));
        B[base + k]          = (short)h;
        B[base + CH + k]     = (short)lo;
        B[base + 2 * CH + k] = (short)h;
    }
}

// ---- K2: 128x128 MFMA GEMM tile, epilogue E=exp(sim) + row/col sum atomics ----
__global__ __launch_bounds__(256) void gemm_exp(
    const short* __restrict__ A, const short* __restrict__ B,
    const float* __restrict__ temp,
    float* __restrict__ E, float* __restrict__ rowsum, float* __restrict__ colsum)
{
    __shared__ __align__(16) short As[128 * 32];
    __shared__ __align__(16) short Bs[128 * 32];
    int bid = blockIdx.x;
    int n = bid / (TT * TT);
    int t = bid % (TT * TT);
    int tm = (t / TT) * 128;
    int tn = (t % TT) * 128;
    const short* Ab = A + (long)n * L * KS;
    const short* Bb = B + (long)n * L * KS;
    int tid = threadIdx.x;
    int lane = tid & 63;
    int w = tid >> 6;
    int wr = (w >> 1) * 64;
    int wc = (w & 1) * 64;

    f32x4 acc[4][4] = {};

    int lrow = lane >> 2;       // 0..15 within 16-row chunk
    int kc8 = (lane & 3) * 8;   // k sub-chunk

    for (int k0 = 0; k0 < KS; k0 += 32) {
        __syncthreads();
#pragma unroll
        for (int j = 0; j < 2; ++j) {
            int c = w * 2 + j;                 // wave-uniform chunk id 0..7
            int row = c * 16 + lrow;
            int ga = tm + row; ga = ga > L - 1 ? L - 1 : ga;
            int gb = tn + row; gb = gb > L - 1 ? L - 1 : gb;
            __builtin_amdgcn_global_load_lds(
                (const __attribute__((address_space(1))) void*)(Ab + (long)ga * KS + k0 + kc8),
                (__attribute__((address_space(3))) void*)(As + c * 512), 16, 0, 0);
            __builtin_amdgcn_global_load_lds(
                (const __attribute__((address_space(1))) void*)(Bb + (long)gb * KS + k0 + kc8),
                (__attribute__((address_space(3))) void*)(Bs + c * 512), 16, 0, 0);
        }
        __syncthreads();

        short8 af[4], bf[4];
        int klo = (lane >> 4) * 8;
        int ra = wr + (lane & 15);
        int rb = wc + (lane & 15);
#pragma unroll
        for (int m = 0; m < 4; ++m) af[m] = *(const short8*)&As[(ra + m * 16) * 32 + klo];
#pragma unroll
        for (int nf = 0; nf < 4; ++nf) bf[nf] = *(const short8*)&Bs[(rb + nf * 16) * 32 + klo];
#pragma unroll
        for (int m = 0; m < 4; ++m)
#pragma unroll
            for (int nf = 0; nf < 4; ++nf)
                acc[m][nf] = __builtin_amdgcn_mfma_f32_16x16x32_bf16(af[m], bf[nf], acc[m][nf], 0, 0, 0);
    }

    // epilogue: sim -> E = exp(sim); partial row/col sums of E
    float scale = temp[0] * (1.0f / 256.0f);
    float rpart[4][4];
#pragma unroll
    for (int m = 0; m < 4; ++m)
#pragma unroll
        for (int j = 0; j < 4; ++j) rpart[m][j] = 0.f;
    float cpart[4] = {0.f, 0.f, 0.f, 0.f};
    int row0 = tm + wr + ((lane >> 4) * 4);
    int col0 = tn + wc + (lane & 15);
#pragma unroll
    for (int m = 0; m < 4; ++m) {
#pragma unroll
        for (int nf = 0; nf < 4; ++nf) {
#pragma unroll
            for (int j = 0; j < 4; ++j) {
                int rr = row0 + m * 16 + j;
                int cc = col0 + nf * 16;
                float e = 0.f;
                if (rr < L && cc < L) {
                    e = __expf(acc[m][nf][j] * scale);
                    E[((long)n * L + rr) * L + cc] = e;
                }
                rpart[m][j] += e;
                cpart[nf] += e;
            }
        }
    }
    // row sums: reduce across the 16 lanes sharing a row
#pragma unroll
    for (int m = 0; m < 4; ++m)
#pragma unroll
        for (int j = 0; j < 4; ++j) {
            float v = rpart[m][j];
            v += __shfl_xor(v, 1); v += __shfl_xor(v, 2);
            v += __shfl_xor(v, 4); v += __shfl_xor(v, 8);
            if ((lane & 15) == 0) {
                int rr = row0 + m * 16 + j;
                if (rr < L) atomicAdd(&rowsum[n * L + rr], v);
            }
        }
    // col sums: reduce across the 4 row-groups
#pragma unroll
    for (int nf = 0; nf < 4; ++nf) {
        float v = cpart[nf];
        v += __shfl_xor(v, 16); v += __shfl_xor(v, 32);
        if ((lane >> 4) == 0) {
            int cc = col0 + nf * 16;
            if (cc < L) atomicAdd(&colsum[n * L + cc], v);
        }
    }
}

// ---- K2.5: reciprocals ----
__global__ void inv_kernel(const float* rowsum, const float* colsum, float* inv_rs, float* inv_cs) {
    int i = blockIdx.x * 256 + threadIdx.x;
    if (i < NB * L) { inv_rs[i] = 1.0f / rowsum[i]; inv_cs[i] = 1.0f / colsum[i]; }
}

// ---- K3: conf = E^2 * inv_rs * inv_cs, write conf + rowmax ----
__global__ __launch_bounds__(256) void conf_row(
    const float* __restrict__ E, const float* __restrict__ inv_rs, const float* __restrict__ inv_cs,
    float* __restrict__ conf, float* __restrict__ rowmax)
{
    int b = blockIdx.x;          // n*L + l
    int n = b / L;
    const f32x4* E4 = (const f32x4*)(E + (long)b * L);
    f32x4* C4 = (f32x4*)(conf + (long)b * L);
    const f32x4* IC4 = (const f32x4*)(inv_cs + n * L);
    float irs = inv_rs[b];
    int tid = threadIdx.x;
    float m = 0.f;
    for (int i = tid; i < L / 4; i += 256) {
        f32x4 e = E4[i];
        f32x4 ic = IC4[i];
        f32x4 c;
#pragma unroll
        for (int k = 0; k < 4; ++k) { c[k] = e[k] * e[k] * irs * ic[k]; m = fmaxf(m, c[k]); }
        C4[i] = c;
    }
#pragma unroll
    for (int off = 1; off < 64; off <<= 1) m = fmaxf(m, __shfl_xor(m, off));
    __shared__ float sm[4];
    int lane = tid & 63, wv = tid >> 6;
    if (lane == 0) sm[wv] = m;
    __syncthreads();
    if (tid == 0) rowmax[b] = fmaxf(fmaxf(sm[0], sm[1]), fmaxf(sm[2], sm[3]));
}

// ---- K4: column maxima via atomicMax on positive-float bits ----
__global__ __launch_bounds__(256) void col_stats(const float* __restrict__ conf, unsigned* __restrict__ colmax)
{
    int bx = blockIdx.x;             // n(2) x cc(19) x rc(32)
    int rc = bx & 31;
    int cc = (bx >> 5) % 19;
    int n = bx / (19 * 32);
    int col = cc * 256 + threadIdx.x;
    if (col >= L) return;
    float m = 0.f;
    const float* p = conf + ((long)n * L + rc * 150) * L + col;
    for (int i = 0; i < 150; ++i) { m = fmaxf(m, *p); p += L; }
    atomicMax(&colmax[n * L + col], __float_as_uint(m));
}

// ---- K5: mconf = conf where (thr & border & row-argmax & col-argmax) ----
__global__ __launch_bounds__(256) void mconf_kernel(
    const float* __restrict__ conf, const float* __restrict__ rowmax,
    const unsigned* __restrict__ colmax, float* __restrict__ mconf)
{
    int b = blockIdx.x / 5;
    int seg = blockIdx.x % 5;
    int n = b / L, l = b % L;
    int off = seg * 1024 + threadIdx.x * 4;
    if (off >= L) return;
    int h0 = l / 80, w0 = l % 80;
    bool bl = (h0 >= 2) && (h0 < 58) && (w0 >= 2) && (w0 < 78);
    float rm = rowmax[b];
    long base = (long)b * L + off;
    f32x4 c = *(const f32x4*)(conf + base);
    f32x4 o;
#pragma unroll
    for (int k = 0; k < 4; ++k) {
        int s = off + k;
        int h1 = s / 80, w1 = s % 80;
        bool bs = (h1 >= 2) && (h1 < 58) && (w1 >= 2) && (w1 < 78);
        float cm = __uint_as_float(colmax[n * L + s]);
        o[k] = (bl && bs && c[k] > 0.2f && c[k] == rm && c[k] == cm) ? c[k] : 0.f;
    }
    *(f32x4*)(mconf + base) = o;
}

extern "C" void kernel_launch(void* const* d_in, const int* in_sizes, int n_in,
                              void* d_out, int out_size, void* d_ws, size_t ws_size,
                              hipStream_t stream)
{
    const float* f0 = (const float*)d_in[0];
    const float* f1 = (const float*)d_in[1];
    const float* temp = (const float*)d_in[2];

    float* conf  = (float*)d_out;
    float* mconf = conf + (long)NB * L * L;   // second half of d_out
    float* E     = mconf;                      // E scratch lives in mconf region

    // bf16 split matrices live temporarily in the conf region (overwritten by K3)
    short* Abf = (short*)d_out;                          // 14.75 MB
    short* Bbf = (short*)((char*)d_out + 32u * 1024u * 1024u);

    float* rowsum = (float*)d_ws;
    float* colsum = rowsum + NB * L;
    float* inv_rs = colsum + NB * L;
    float* inv_cs = inv_rs + NB * L;
    float* rowmax = inv_cs + NB * L;
    unsigned* colmax = (unsigned*)(rowmax + NB * L);

    init_stats<<<(NB * L + 255) / 256, 256, 0, stream>>>(rowsum, colsum, colmax);
    convert_kernel<<<(NB * L * CH + 255) / 256, 256, 0, stream>>>(f0, f1, Abf, Bbf);
    gemm_exp<<<NB * TT * TT, 256, 0, stream>>>(Abf, Bbf, temp, E, rowsum, colsum);
    inv_kernel<<<(NB * L + 255) / 256, 256, 0, stream>>>(rowsum, colsum, inv_rs, inv_cs);
    conf_row<<<NB * L, 256, 0, stream>>>(E, inv_rs, inv_cs, conf, rowmax);
    col_stats<<<NB * 19 * 32, 256, 0, stream>>>(conf, colmax);
    mconf_kernel<<<NB * L * 5, 256, 0, stream>>>(conf, rowmax, colmax, mconf);
}

// Round 3
// 540.453 us; speedup vs baseline: 1.1637x; 1.1637x over previous
//
#include <hip/hip_runtime.h>
#include <hip/hip_bf16.h>

#define L 4800
#define CH 256
#define KS 768       // split-K: [hi, hi, lo] x [hi, lo, hi]
#define NB 2
#define TT 38        // ceil(4800/128)

typedef short short8 __attribute__((ext_vector_type(8)));
typedef float f32x4 __attribute__((ext_vector_type(4)));
typedef _Float16 h16;
typedef _Float16 h16x8 __attribute__((ext_vector_type(8)));

__device__ __forceinline__ unsigned short f2bf(float f) {
    unsigned u = __float_as_uint(f);
    unsigned r = (u + 0x7FFF + ((u >> 16) & 1)) >> 16;   // RNE
    return (unsigned short)r;
}
__device__ __forceinline__ float bf2f(unsigned short h) {
    return __uint_as_float(((unsigned)h) << 16);
}

// ---- K0: zero the atomic-accumulated stats ----
__global__ void init_stats(float* rowsum, float* colsum, unsigned* colmax, unsigned* cand_cnt) {
    int i = blockIdx.x * 256 + threadIdx.x;
    if (i < NB * L) { rowsum[i] = 0.f; colsum[i] = 0.f; colmax[i] = 0u; }
    if (i == 0) cand_cnt[0] = 0u;
}

// ---- K1: fp32 -> bf16 hi/lo split matrices ----
__global__ void convert_kernel(const float* __restrict__ f0, const float* __restrict__ f1,
                               short* __restrict__ A, short* __restrict__ B) {
    int idx = blockIdx.x * 256 + threadIdx.x;
    if (idx >= NB * L * CH) return;
    int k = idx % CH;
    int r = (idx / CH) % L;
    int n = idx / (CH * L);
    long base = ((long)(n * L + r)) * KS;
    {
        float f = f0[idx];
        unsigned short h = f2bf(f);
        unsigned short lo = f2bf(f - bf2f(h));
        A[base + k]          = (short)h;
        A[base + CH + k]     = (short)h;
        A[base + 2 * CH + k] = (short)lo;
    }
    {
        float f = f1[idx];
        unsigned short h = f2bf(f);
        unsigned short lo = f2bf(f - bf2f(h));
        B[base + k]          = (short)h;
        B[base + CH + k]     = (short)lo;
        B[base + 2 * CH + k] = (short)h;
    }
}

// ---- K2: 128x128 MFMA GEMM tile, epilogue E=exp(sim) (fp16) + row/col sum atomics ----
__global__ __launch_bounds__(256) void gemm_exp(
    const short* __restrict__ A, const short* __restrict__ B,
    const float* __restrict__ temp,
    h16* __restrict__ E, float* __restrict__ rowsum, float* __restrict__ colsum)
{
    __shared__ __align__(16) short As[128 * 32];
    __shared__ __align__(16) short Bs[128 * 32];
    int bid = blockIdx.x;
    int n = bid / (TT * TT);
    int t = bid % (TT * TT);
    int tm = (t / TT) * 128;
    int tn = (t % TT) * 128;
    const short* Ab = A + (long)n * L * KS;
    const short* Bb = B + (long)n * L * KS;
    int tid = threadIdx.x;
    int lane = tid & 63;
    int w = tid >> 6;
    int wr = (w >> 1) * 64;
    int wc = (w & 1) * 64;

    f32x4 acc[4][4] = {};

    int lrow = lane >> 2;       // 0..15 within 16-row chunk
    int kc8 = (lane & 3) * 8;   // k sub-chunk

    for (int k0 = 0; k0 < KS; k0 += 32) {
        __syncthreads();
#pragma unroll
        for (int j = 0; j < 2; ++j) {
            int c = w * 2 + j;                 // wave-uniform chunk id 0..7
            int row = c * 16 + lrow;
            int ga = tm + row; ga = ga > L - 1 ? L - 1 : ga;
            int gb = tn + row; gb = gb > L - 1 ? L - 1 : gb;
            __builtin_amdgcn_global_load_lds(
                (const __attribute__((address_space(1))) void*)(Ab + (long)ga * KS + k0 + kc8),
                (__attribute__((address_space(3))) void*)(As + c * 512), 16, 0, 0);
            __builtin_amdgcn_global_load_lds(
                (const __attribute__((address_space(1))) void*)(Bb + (long)gb * KS + k0 + kc8),
                (__attribute__((address_space(3))) void*)(Bs + c * 512), 16, 0, 0);
        }
        __syncthreads();

        short8 af[4], bf[4];
        int klo = (lane >> 4) * 8;
        int ra = wr + (lane & 15);
        int rb = wc + (lane & 15);
#pragma unroll
        for (int m = 0; m < 4; ++m) af[m] = *(const short8*)&As[(ra + m * 16) * 32 + klo];
#pragma unroll
        for (int nf = 0; nf < 4; ++nf) bf[nf] = *(const short8*)&Bs[(rb + nf * 16) * 32 + klo];
#pragma unroll
        for (int m = 0; m < 4; ++m)
#pragma unroll
            for (int nf = 0; nf < 4; ++nf)
                acc[m][nf] = __builtin_amdgcn_mfma_f32_16x16x32_bf16(af[m], bf[nf], acc[m][nf], 0, 0, 0);
    }

    // epilogue: sim -> e = exp(sim); store fp16 E; partial row/col sums of e (fp32)
    float scale = temp[0] * (1.0f / 256.0f);
    float rpart[4][4];
#pragma unroll
    for (int m = 0; m < 4; ++m)
#pragma unroll
        for (int j = 0; j < 4; ++j) rpart[m][j] = 0.f;
    float cpart[4] = {0.f, 0.f, 0.f, 0.f};
    int row0 = tm + wr + ((lane >> 4) * 4);
    int col0 = tn + wc + (lane & 15);
#pragma unroll
    for (int m = 0; m < 4; ++m) {
#pragma unroll
        for (int nf = 0; nf < 4; ++nf) {
#pragma unroll
            for (int j = 0; j < 4; ++j) {
                int rr = row0 + m * 16 + j;
                int cc = col0 + nf * 16;
                float e = 0.f;
                if (rr < L && cc < L) {
                    e = __expf(acc[m][nf][j] * scale);
                    E[((long)n * L + rr) * L + cc] = (h16)e;
                }
                rpart[m][j] += e;
                cpart[nf] += e;
            }
        }
    }
#pragma unroll
    for (int m = 0; m < 4; ++m)
#pragma unroll
        for (int j = 0; j < 4; ++j) {
            float v = rpart[m][j];
            v += __shfl_xor(v, 1); v += __shfl_xor(v, 2);
            v += __shfl_xor(v, 4); v += __shfl_xor(v, 8);
            if ((lane & 15) == 0) {
                int rr = row0 + m * 16 + j;
                if (rr < L) atomicAdd(&rowsum[n * L + rr], v);
            }
        }
#pragma unroll
    for (int nf = 0; nf < 4; ++nf) {
        float v = cpart[nf];
        v += __shfl_xor(v, 16); v += __shfl_xor(v, 32);
        if ((lane >> 4) == 0) {
            int cc = col0 + nf * 16;
            if (cc < L) atomicAdd(&colsum[n * L + cc], v);
        }
    }
}

// ---- K2.5: reciprocals ----
__global__ void inv_kernel(const float* rowsum, const float* colsum, float* inv_rs, float* inv_cs) {
    int i = blockIdx.x * 256 + threadIdx.x;
    if (i < NB * L) { inv_rs[i] = 1.0f / rowsum[i]; inv_cs[i] = 1.0f / colsum[i]; }
}

// ---- K3: conf = E^2*irs*ics, write conf + rowmax (direct) + candidates (conf>thr) ----
__global__ __launch_bounds__(256) void conf_row(
    const h16* __restrict__ E, const float* __restrict__ inv_rs, const float* __restrict__ inv_cs,
    float* __restrict__ conf, float* __restrict__ rowmax,
    unsigned* __restrict__ cand, unsigned* __restrict__ cand_cnt, unsigned cand_cap)
{
    int b = blockIdx.x;          // n*L + l
    int n = b / L;
    const h16x8* E8 = (const h16x8*)(E + (long)b * L);
    const f32x4* IC4 = (const f32x4*)(inv_cs + n * L);
    float* Crow = conf + (long)b * L;
    float irs = inv_rs[b];
    int tid = threadIdx.x;
    float m = 0.f;
    for (int i = tid; i < L / 8; i += 256) {
        h16x8 e8 = E8[i];
        f32x4 ic0 = IC4[2 * i], ic1 = IC4[2 * i + 1];
        f32x4 c0, c1;
#pragma unroll
        for (int k = 0; k < 4; ++k) {
            float e = (float)e8[k];
            float tt = (e * e) * irs;          // same assoc as col_max
            c0[k] = tt * ic0[k];
            m = fmaxf(m, c0[k]);
        }
#pragma unroll
        for (int k = 0; k < 4; ++k) {
            float e = (float)e8[4 + k];
            float tt = (e * e) * irs;
            c1[k] = tt * ic1[k];
            m = fmaxf(m, c1[k]);
        }
        *(f32x4*)&Crow[i * 8] = c0;
        *(f32x4*)&Crow[i * 8 + 4] = c1;
#pragma unroll
        for (int k = 0; k < 4; ++k) {
            if (c0[k] > 0.2f) {
                unsigned pos = atomicAdd(cand_cnt, 1u);
                if (pos < cand_cap) cand[pos] = (unsigned)b * L + (unsigned)(i * 8 + k);
            }
            if (c1[k] > 0.2f) {
                unsigned pos = atomicAdd(cand_cnt, 1u);
                if (pos < cand_cap) cand[pos] = (unsigned)b * L + (unsigned)(i * 8 + 4 + k);
            }
        }
    }
#pragma unroll
    for (int off = 1; off < 64; off <<= 1) m = fmaxf(m, __shfl_xor(m, off));
    __shared__ float sm[4];
    int lane = tid & 63, wv = tid >> 6;
    if (lane == 0) sm[wv] = m;
    __syncthreads();
    if (tid == 0) rowmax[b] = fmaxf(fmaxf(sm[0], sm[1]), fmaxf(sm[2], sm[3]));
}

// ---- K4: column maxima of conf from E (monotone-equal bits) ----
__global__ __launch_bounds__(256) void col_max(
    const h16* __restrict__ E, const float* __restrict__ inv_rs, const float* __restrict__ inv_cs,
    unsigned* __restrict__ colmax)
{
    int bx = blockIdx.x;             // n(2) x cc(19) x rc(32)
    int rc = bx & 31;
    int cc = (bx >> 5) % 19;
    int n = bx / (19 * 32);
    int col = cc * 256 + threadIdx.x;
    if (col >= L) return;
    const h16* p = E + ((long)n * L + rc * 150) * L + col;
    const float* irs = inv_rs + n * L + rc * 150;
    float m = 0.f;
    for (int i = 0; i < 150; ++i) {
        float e = (float)(*p);
        float tt = (e * e) * irs[i];           // same assoc as conf_row
        m = fmaxf(m, tt);
        p += L;
    }
    float v = m * inv_cs[n * L + col];
    atomicMax(&colmax[n * L + col], __float_as_uint(v));
}

// ---- K5: zero-fill mconf ----
__global__ __launch_bounds__(256) void fill_zero(f32x4* __restrict__ p, long n4) {
    long i = (long)blockIdx.x * 256 + threadIdx.x;
    long stride = (long)gridDim.x * 256;
    f32x4 z = {0.f, 0.f, 0.f, 0.f};
    for (; i < n4; i += stride) p[i] = z;
}

// ---- K6: scatter matches into mconf ----
__global__ __launch_bounds__(256) void cand_kernel(
    const unsigned* __restrict__ cand_cnt, const unsigned* __restrict__ cand, unsigned cand_cap,
    const float* __restrict__ conf, const float* __restrict__ rowmax,
    const unsigned* __restrict__ colmax, float* __restrict__ mconf)
{
    unsigned cnt = cand_cnt[0];
    if (cnt > cand_cap) cnt = cand_cap;
    for (unsigned i = blockIdx.x * 256 + threadIdx.x; i < cnt; i += gridDim.x * 256) {
        unsigned idx = cand[i];
        unsigned b = idx / L, s = idx % L;
        unsigned n = b / L, l = b % L;
        int h0 = l / 80, w0 = l % 80;
        int h1 = s / 80, w1 = s % 80;
        bool ok = (h0 >= 2) && (h0 < 58) && (w0 >= 2) && (w0 < 78)
               && (h1 >= 2) && (h1 < 58) && (w1 >= 2) && (w1 < 78);
        float c = conf[idx];
        if (ok && c == rowmax[b] && c == __uint_as_float(colmax[n * L + s]))
            mconf[idx] = c;
    }
}

extern "C" void kernel_launch(void* const* d_in, const int* in_sizes, int n_in,
                              void* d_out, int out_size, void* d_ws, size_t ws_size,
                              hipStream_t stream)
{
    const float* f0 = (const float*)d_in[0];
    const float* f1 = (const float*)d_in[1];
    const float* temp = (const float*)d_in[2];

    float* conf  = (float*)d_out;
    float* mconf = conf + (long)NB * L * L;   // second half of d_out
    h16*   E     = (h16*)mconf;               // fp16 E scratch in mconf region (92 MB)

    // bf16 split matrices live temporarily in the conf region (overwritten by conf_row)
    short* Abf = (short*)d_out;                          // 14.75 MB
    short* Bbf = (short*)((char*)d_out + 32u * 1024u * 1024u);

    float* rowsum = (float*)d_ws;
    float* colsum = rowsum + NB * L;
    float* inv_rs = colsum + NB * L;
    float* inv_cs = inv_rs + NB * L;
    float* rowmax = inv_cs + NB * L;
    unsigned* colmax = (unsigned*)(rowmax + NB * L);
    unsigned* cand_cnt = colmax + NB * L;
    unsigned* cand = cand_cnt + 1;
    long stats_bytes = (char*)cand - (char*)d_ws;
    long cap_l = ((long)ws_size - stats_bytes) / 4;
    if (cap_l < 0) cap_l = 0;
    if (cap_l > (4 << 20)) cap_l = 4 << 20;
    unsigned cand_cap = (unsigned)cap_l;

    init_stats<<<(NB * L + 255) / 256, 256, 0, stream>>>(rowsum, colsum, colmax, cand_cnt);
    convert_kernel<<<(NB * L * CH + 255) / 256, 256, 0, stream>>>(f0, f1, Abf, Bbf);
    gemm_exp<<<NB * TT * TT, 256, 0, stream>>>(Abf, Bbf, temp, E, rowsum, colsum);
    inv_kernel<<<(NB * L + 255) / 256, 256, 0, stream>>>(rowsum, colsum, inv_rs, inv_cs);
    conf_row<<<NB * L, 256, 0, stream>>>(E, inv_rs, inv_cs, conf, rowmax, cand, cand_cnt, cand_cap);
    col_max<<<NB * 19 * 32, 256, 0, stream>>>(E, inv_rs, inv_cs, colmax);
    fill_zero<<<2048, 256, 0, stream>>>((f32x4*)mconf, (long)NB * L * L / 4);
    cand_kernel<<<128, 256, 0, stream>>>(cand_cnt, cand, cand_cap, conf, rowmax, colmax, mconf);
}

// Round 4
// 531.835 us; speedup vs baseline: 1.1825x; 1.0162x over previous
//
#include <hip/hip_runtime.h>

#define L 4800
#define CH 256
#define NB 2
#define TT 38        // ceil(4800/128)

typedef float f32x4 __attribute__((ext_vector_type(4)));
typedef _Float16 h16;
typedef _Float16 h16x4 __attribute__((ext_vector_type(4)));
typedef _Float16 h16x8 __attribute__((ext_vector_type(8)));

// ---- K1: fp32 -> fp16 convert (elementwise) + zero stats ----
__global__ __launch_bounds__(256) void convert_init(
    const float* __restrict__ f0, const float* __restrict__ f1,
    h16* __restrict__ A, h16* __restrict__ B,
    float* __restrict__ rowsum, float* __restrict__ colsum,
    unsigned* __restrict__ colmax, unsigned* __restrict__ cand_cnt)
{
    int idx = blockIdx.x * 256 + threadIdx.x;
    if (idx < NB * L) { rowsum[idx] = 0.f; colsum[idx] = 0.f; colmax[idx] = 0u; }
    if (idx == 0) cand_cnt[0] = 0u;
    if (idx >= NB * L * CH / 4) return;
    f32x4 a = ((const f32x4*)f0)[idx];
    f32x4 b = ((const f32x4*)f1)[idx];
    h16x4 ah, bh;
#pragma unroll
    for (int k = 0; k < 4; ++k) { ah[k] = (h16)a[k]; bh[k] = (h16)b[k]; }
    ((h16x4*)A)[idx] = ah;
    ((h16x4*)B)[idx] = bh;
}

// ---- K2: 128x128 MFMA f16 GEMM (K=256), epilogue E=exp(sim) fp16 + row/col sums ----
__global__ __launch_bounds__(256) void gemm_exp(
    const h16* __restrict__ A, const h16* __restrict__ B,
    const float* __restrict__ temp,
    h16* __restrict__ E, float* __restrict__ rowsum, float* __restrict__ colsum)
{
    __shared__ __align__(16) h16 As[128 * 32];
    __shared__ __align__(16) h16 Bs[128 * 32];
    int bid = blockIdx.x;
    int n = bid / (TT * TT);
    int t = bid % (TT * TT);
    int tm = (t / TT) * 128;
    int tn = (t % TT) * 128;
    const h16* Ab = A + (long)n * L * CH;
    const h16* Bb = B + (long)n * L * CH;
    int tid = threadIdx.x;
    int lane = tid & 63;
    int w = tid >> 6;
    int wr = (w >> 1) * 64;
    int wc = (w & 1) * 64;

    f32x4 acc[4][4] = {};

    int lrow = lane >> 2;       // 0..15 within 16-row chunk
    int kc8 = (lane & 3) * 8;   // k sub-chunk

    for (int k0 = 0; k0 < CH; k0 += 32) {
        __syncthreads();
#pragma unroll
        for (int j = 0; j < 2; ++j) {
            int c = w * 2 + j;                 // wave-uniform chunk id 0..7
            int row = c * 16 + lrow;
            int ga = tm + row; ga = ga > L - 1 ? L - 1 : ga;
            int gb = tn + row; gb = gb > L - 1 ? L - 1 : gb;
            __builtin_amdgcn_global_load_lds(
                (const __attribute__((address_space(1))) void*)(Ab + (long)ga * CH + k0 + kc8),
                (__attribute__((address_space(3))) void*)(As + c * 512), 16, 0, 0);
            __builtin_amdgcn_global_load_lds(
                (const __attribute__((address_space(1))) void*)(Bb + (long)gb * CH + k0 + kc8),
                (__attribute__((address_space(3))) void*)(Bs + c * 512), 16, 0, 0);
        }
        __syncthreads();

        h16x8 af[4], bf[4];
        int klo = (lane >> 4) * 8;
        int ra = wr + (lane & 15);
        int rb = wc + (lane & 15);
#pragma unroll
        for (int m = 0; m < 4; ++m) af[m] = *(const h16x8*)&As[(ra + m * 16) * 32 + klo];
#pragma unroll
        for (int nf = 0; nf < 4; ++nf) bf[nf] = *(const h16x8*)&Bs[(rb + nf * 16) * 32 + klo];
#pragma unroll
        for (int m = 0; m < 4; ++m)
#pragma unroll
            for (int nf = 0; nf < 4; ++nf)
                acc[m][nf] = __builtin_amdgcn_mfma_f32_16x16x32_f16(af[m], bf[nf], acc[m][nf], 0, 0, 0);
    }

    // epilogue: e = exp(sim*scale); store fp16 E; partial row/col sums (fp32)
    float scale = temp[0] * (1.0f / 256.0f);
    float rpart[4][4];
#pragma unroll
    for (int m = 0; m < 4; ++m)
#pragma unroll
        for (int j = 0; j < 4; ++j) rpart[m][j] = 0.f;
    float cpart[4] = {0.f, 0.f, 0.f, 0.f};
    int row0 = tm + wr + ((lane >> 4) * 4);
    int col0 = tn + wc + (lane & 15);
#pragma unroll
    for (int m = 0; m < 4; ++m) {
#pragma unroll
        for (int nf = 0; nf < 4; ++nf) {
#pragma unroll
            for (int j = 0; j < 4; ++j) {
                int rr = row0 + m * 16 + j;
                int cc = col0 + nf * 16;
                float e = 0.f;
                if (rr < L && cc < L) {
                    e = __expf(acc[m][nf][j] * scale);
                    E[((long)n * L + rr) * L + cc] = (h16)e;
                }
                rpart[m][j] += e;
                cpart[nf] += e;
            }
        }
    }
#pragma unroll
    for (int m = 0; m < 4; ++m)
#pragma unroll
        for (int j = 0; j < 4; ++j) {
            float v = rpart[m][j];
            v += __shfl_xor(v, 1); v += __shfl_xor(v, 2);
            v += __shfl_xor(v, 4); v += __shfl_xor(v, 8);
            if ((lane & 15) == 0) {
                int rr = row0 + m * 16 + j;
                if (rr < L) atomicAdd(&rowsum[n * L + rr], v);
            }
        }
#pragma unroll
    for (int nf = 0; nf < 4; ++nf) {
        float v = cpart[nf];
        v += __shfl_xor(v, 16); v += __shfl_xor(v, 32);
        if ((lane >> 4) == 0) {
            int cc = col0 + nf * 16;
            if (cc < L) atomicAdd(&colsum[n * L + cc], v);
        }
    }
}

// ---- K3: reciprocals ----
__global__ void inv_kernel(const float* rowsum, const float* colsum, float* inv_rs, float* inv_cs) {
    int i = blockIdx.x * 256 + threadIdx.x;
    if (i < NB * L) { inv_rs[i] = 1.0f / rowsum[i]; inv_cs[i] = 1.0f / colsum[i]; }
}

// ---- K4: conf = E^2*irs*ics; write conf + rowmax + candidates; optionally zero mconf ----
__global__ __launch_bounds__(256) void conf_row(
    const h16* __restrict__ E, const float* __restrict__ inv_rs, const float* __restrict__ inv_cs,
    float* __restrict__ conf, float* __restrict__ rowmax,
    float* __restrict__ mzero,            // nullptr -> skip
    unsigned* __restrict__ cand, unsigned* __restrict__ cand_cnt, unsigned cand_cap)
{
    int b = blockIdx.x;          // n*L + l
    int n = b / L;
    const h16x8* E8 = (const h16x8*)(E + (long)b * L);
    const f32x4* IC4 = (const f32x4*)(inv_cs + n * L);
    float* Crow = conf + (long)b * L;
    float irs = inv_rs[b];
    int tid = threadIdx.x;
    float m = 0.f;
    for (int i = tid; i < L / 8; i += 256) {
        h16x8 e8 = E8[i];
        f32x4 ic0 = IC4[2 * i], ic1 = IC4[2 * i + 1];
        f32x4 c0, c1;
#pragma unroll
        for (int k = 0; k < 4; ++k) {
            float e = (float)e8[k];
            float tt = (e * e) * irs;          // same assoc as col_max
            c0[k] = tt * ic0[k];
            m = fmaxf(m, c0[k]);
        }
#pragma unroll
        for (int k = 0; k < 4; ++k) {
            float e = (float)e8[4 + k];
            float tt = (e * e) * irs;
            c1[k] = tt * ic1[k];
            m = fmaxf(m, c1[k]);
        }
        *(f32x4*)&Crow[i * 8] = c0;
        *(f32x4*)&Crow[i * 8 + 4] = c1;
#pragma unroll
        for (int k = 0; k < 4; ++k) {
            if (c0[k] > 0.2f) {
                unsigned pos = atomicAdd(cand_cnt, 1u);
                if (pos < cand_cap) cand[pos] = (unsigned)b * L + (unsigned)(i * 8 + k);
            }
            if (c1[k] > 0.2f) {
                unsigned pos = atomicAdd(cand_cnt, 1u);
                if (pos < cand_cap) cand[pos] = (unsigned)b * L + (unsigned)(i * 8 + 4 + k);
            }
        }
    }
    if (mzero) {
        f32x4* M4 = (f32x4*)(mzero + (long)b * L);
        f32x4 z = {0.f, 0.f, 0.f, 0.f};
        for (int i = tid; i < L / 4; i += 256) M4[i] = z;
    }
#pragma unroll
    for (int off = 1; off < 64; off <<= 1) m = fmaxf(m, __shfl_xor(m, off));
    __shared__ float sm[4];
    int lane = tid & 63, wv = tid >> 6;
    if (lane == 0) sm[wv] = m;
    __syncthreads();
    if (tid == 0) rowmax[b] = fmaxf(fmaxf(sm[0], sm[1]), fmaxf(sm[2], sm[3]));
}

// ---- K5: column maxima of conf from E (monotone-equal bits) ----
__global__ __launch_bounds__(256) void col_max(
    const h16* __restrict__ E, const float* __restrict__ inv_rs, const float* __restrict__ inv_cs,
    unsigned* __restrict__ colmax)
{
    int bx = blockIdx.x;             // n(2) x cc(19) x rc(32)
    int rc = bx & 31;
    int cc = (bx >> 5) % 19;
    int n = bx / (19 * 32);
    int col = cc * 256 + threadIdx.x;
    if (col >= L) return;
    const h16* p = E + ((long)n * L + rc * 150) * L + col;
    const float* irs = inv_rs + n * L + rc * 150;
    float m = 0.f;
    for (int i = 0; i < 150; ++i) {
        float e = (float)(*p);
        float tt = (e * e) * irs[i];           // same assoc as conf_row
        m = fmaxf(m, tt);
        p += L;
    }
    float v = m * inv_cs[n * L + col];
    atomicMax(&colmax[n * L + col], __float_as_uint(v));
}

// ---- K5b (fallback only): zero-fill mconf ----
__global__ __launch_bounds__(256) void fill_zero(f32x4* __restrict__ p, long n4) {
    long i = (long)blockIdx.x * 256 + threadIdx.x;
    long stride = (long)gridDim.x * 256;
    f32x4 z = {0.f, 0.f, 0.f, 0.f};
    for (; i < n4; i += stride) p[i] = z;
}

// ---- K6: scatter matches into mconf ----
__global__ __launch_bounds__(256) void cand_kernel(
    const unsigned* __restrict__ cand_cnt, const unsigned* __restrict__ cand, unsigned cand_cap,
    const float* __restrict__ conf, const float* __restrict__ rowmax,
    const unsigned* __restrict__ colmax, float* __restrict__ mconf)
{
    unsigned cnt = cand_cnt[0];
    if (cnt > cand_cap) cnt = cand_cap;
    for (unsigned i = blockIdx.x * 256 + threadIdx.x; i < cnt; i += gridDim.x * 256) {
        unsigned idx = cand[i];
        unsigned b = idx / L, s = idx % L;
        unsigned n = b / L, l = b % L;
        int h0 = l / 80, w0 = l % 80;
        int h1 = s / 80, w1 = s % 80;
        bool ok = (h0 >= 2) && (h0 < 58) && (w0 >= 2) && (w0 < 78)
               && (h1 >= 2) && (h1 < 58) && (w1 >= 2) && (w1 < 78);
        float c = conf[idx];
        if (ok && c == rowmax[b] && c == __uint_as_float(colmax[n * L + s]))
            mconf[idx] = c;
    }
}

extern "C" void kernel_launch(void* const* d_in, const int* in_sizes, int n_in,
                              void* d_out, int out_size, void* d_ws, size_t ws_size,
                              hipStream_t stream)
{
    const float* f0 = (const float*)d_in[0];
    const float* f1 = (const float*)d_in[1];
    const float* temp = (const float*)d_in[2];

    float* conf  = (float*)d_out;
    float* mconf = conf + (long)NB * L * L;   // second half of d_out

    // A/B fp16 matrices live temporarily in the conf region (overwritten by conf_row)
    h16* Abf = (h16*)d_out;                               // 4.92 MB
    h16* Bbf = (h16*)((char*)d_out + 8u * 1024u * 1024u); // 4.92 MB

    float* rowsum = (float*)d_ws;
    float* colsum = rowsum + NB * L;
    float* inv_rs = colsum + NB * L;
    float* inv_cs = inv_rs + NB * L;
    float* rowmax = inv_cs + NB * L;
    unsigned* colmax = (unsigned*)(rowmax + NB * L);
    unsigned* cand_cnt = colmax + NB * L;
    unsigned* cand = cand_cnt + 1;
    const unsigned cand_cap = 1u << 20;                   // 4 MB
    size_t stats_end = (size_t)((char*)(cand + cand_cap) - (char*)d_ws);
    size_t E_off = (stats_end + 255) & ~(size_t)255;
    size_t E_bytes = (size_t)NB * L * L * 2;              // 92.16 MB
    bool E_in_ws = ws_size >= E_off + E_bytes;
    h16* E = E_in_ws ? (h16*)((char*)d_ws + E_off) : (h16*)mconf;

    convert_init<<<(NB * L * CH / 4 + 255) / 256, 256, 0, stream>>>(
        f0, f1, Abf, Bbf, rowsum, colsum, colmax, cand_cnt);
    gemm_exp<<<NB * TT * TT, 256, 0, stream>>>(Abf, Bbf, temp, E, rowsum, colsum);
    inv_kernel<<<(NB * L + 255) / 256, 256, 0, stream>>>(rowsum, colsum, inv_rs, inv_cs);
    conf_row<<<NB * L, 256, 0, stream>>>(E, inv_rs, inv_cs, conf, rowmax,
                                         E_in_ws ? mconf : (float*)nullptr,
                                         cand, cand_cnt, cand_cap);
    col_max<<<NB * 19 * 32, 256, 0, stream>>>(E, inv_rs, inv_cs, colmax);
    if (!E_in_ws)
        fill_zero<<<2048, 256, 0, stream>>>((f32x4*)mconf, (long)NB * L * L / 4);
    cand_kernel<<<128, 256, 0, stream>>>(cand_cnt, cand, cand_cap, conf, rowmax, colmax, mconf);
}

// Round 6
// 475.223 us; speedup vs baseline: 1.3234x; 1.1191x over previous
//
#include <hip/hip_runtime.h>

#define L 4800
#define CH 256
#define NB 2
#define TT 38              // ceil(4800/128)
#define NBL (NB * L)       // 9600
#define THRF 0.2f

typedef float f32x4 __attribute__((ext_vector_type(4)));
typedef _Float16 h16;
typedef _Float16 h16x4 __attribute__((ext_vector_type(4)));
typedef _Float16 h16x8 __attribute__((ext_vector_type(8)));

// ---- K1: fp32 -> fp16 convert (elementwise) ----
__global__ __launch_bounds__(256) void convert_kernel(
    const float* __restrict__ f0, const float* __restrict__ f1,
    h16* __restrict__ A, h16* __restrict__ B)
{
    int idx = blockIdx.x * 256 + threadIdx.x;
    if (idx >= NB * L * CH / 4) return;
    f32x4 a = ((const f32x4*)f0)[idx];
    f32x4 b = ((const f32x4*)f1)[idx];
    h16x4 ah, bh;
#pragma unroll
    for (int k = 0; k < 4; ++k) { ah[k] = (h16)a[k]; bh[k] = (h16)b[k]; }
    ((h16x4*)A)[idx] = ah;
    ((h16x4*)B)[idx] = bh;
}

// ---- K2: GEMM pass 1 — deterministic per-tile row/col sums of exp(sim) ----
__global__ __launch_bounds__(256) void gemm_pass1(
    const h16* __restrict__ A, const h16* __restrict__ B,
    const float* __restrict__ temp,
    float* __restrict__ rs_part, float* __restrict__ cs_part)
{
    __shared__ __align__(16) h16 As[128 * 32];
    __shared__ __align__(16) h16 Bs[128 * 32];
    __shared__ float rp_lds[128][2];
    __shared__ float cp_lds[128][2];
    int bid = blockIdx.x;
    int n = bid / (TT * TT);
    int t = bid % (TT * TT);
    int tm = (t / TT) * 128;
    int tn = (t % TT) * 128;
    const h16* Ab = A + (long)n * L * CH;
    const h16* Bb = B + (long)n * L * CH;
    int tid = threadIdx.x;
    int lane = tid & 63;
    int w = tid >> 6;
    int wr = (w >> 1) * 64;
    int wc = (w & 1) * 64;

    f32x4 acc[4][4] = {};
    int lrow = lane >> 2;
    int kc8 = (lane & 3) * 8;

    for (int k0 = 0; k0 < CH; k0 += 32) {
        __syncthreads();
#pragma unroll
        for (int j = 0; j < 2; ++j) {
            int c = w * 2 + j;
            int row = c * 16 + lrow;
            int ga = tm + row; ga = ga > L - 1 ? L - 1 : ga;
            int gb = tn + row; gb = gb > L - 1 ? L - 1 : gb;
            __builtin_amdgcn_global_load_lds(
                (const __attribute__((address_space(1))) void*)(Ab + (long)ga * CH + k0 + kc8),
                (__attribute__((address_space(3))) void*)(As + c * 512), 16, 0, 0);
            __builtin_amdgcn_global_load_lds(
                (const __attribute__((address_space(1))) void*)(Bb + (long)gb * CH + k0 + kc8),
                (__attribute__((address_space(3))) void*)(Bs + c * 512), 16, 0, 0);
        }
        __syncthreads();

        h16x8 af[4], bf[4];
        int klo = (lane >> 4) * 8;
        int ra = wr + (lane & 15);
        int rb = wc + (lane & 15);
#pragma unroll
        for (int m = 0; m < 4; ++m) af[m] = *(const h16x8*)&As[(ra + m * 16) * 32 + klo];
#pragma unroll
        for (int nf = 0; nf < 4; ++nf) bf[nf] = *(const h16x8*)&Bs[(rb + nf * 16) * 32 + klo];
#pragma unroll
        for (int m = 0; m < 4; ++m)
#pragma unroll
            for (int nf = 0; nf < 4; ++nf)
                acc[m][nf] = __builtin_amdgcn_mfma_f32_16x16x32_f16(af[m], bf[nf], acc[m][nf], 0, 0, 0);
    }

    float scale = temp[0] * (1.0f / 256.0f);
    float rpart[4][4];
#pragma unroll
    for (int m = 0; m < 4; ++m)
#pragma unroll
        for (int j = 0; j < 4; ++j) rpart[m][j] = 0.f;
    float cpart[4] = {0.f, 0.f, 0.f, 0.f};
    int row0 = tm + wr + ((lane >> 4) * 4);
    int col0 = tn + wc + (lane & 15);
#pragma unroll
    for (int m = 0; m < 4; ++m)
#pragma unroll
        for (int nf = 0; nf < 4; ++nf)
#pragma unroll
            for (int j = 0; j < 4; ++j) {
                int rr = row0 + m * 16 + j;
                int cc = col0 + nf * 16;
                float e = 0.f;
                if (rr < L && cc < L) e = __expf(acc[m][nf][j] * scale);
                rpart[m][j] += e;
                cpart[nf] += e;
            }
    // row partials: reduce across the 16 lanes sharing a row, one writer per slot
#pragma unroll
    for (int m = 0; m < 4; ++m)
#pragma unroll
        for (int j = 0; j < 4; ++j) {
            float v = rpart[m][j];
            v += __shfl_xor(v, 1); v += __shfl_xor(v, 2);
            v += __shfl_xor(v, 4); v += __shfl_xor(v, 8);
            if ((lane & 15) == 0)
                rp_lds[wr + (lane >> 4) * 4 + m * 16 + j][w & 1] = v;
        }
    // col partials: reduce across the 4 row-groups, one writer per slot
#pragma unroll
    for (int nf = 0; nf < 4; ++nf) {
        float v = cpart[nf];
        v += __shfl_xor(v, 16); v += __shfl_xor(v, 32);
        if (lane < 16)
            cp_lds[wc + lane + nf * 16][w >> 1] = v;
    }
    __syncthreads();
    if (tid < 128) {
        int rr = tm + tid;
        if (rr < L)
            rs_part[(long)(t % TT) * NBL + n * L + rr] = rp_lds[tid][0] + rp_lds[tid][1];
    } else {
        int c2 = tid - 128;
        int cc = tn + c2;
        if (cc < L)
            cs_part[(long)(t / TT) * NBL + n * L + cc] = cp_lds[c2][0] + cp_lds[c2][1];
    }
}

// ---- K3: fixed-order reduce of partials -> reciprocals ----
__global__ __launch_bounds__(256) void reduce_inv(
    const float* __restrict__ rs_part, const float* __restrict__ cs_part,
    float* __restrict__ inv_rs, float* __restrict__ inv_cs)
{
    int i = blockIdx.x * 256 + threadIdx.x;
    if (i < NBL) {
        float s = 0.f;
        for (int t = 0; t < TT; ++t) s += rs_part[(long)t * NBL + i];
        inv_rs[i] = 1.0f / s;
    } else if (i < 2 * NBL) {
        int b = i - NBL;
        float s = 0.f;
        for (int t = 0; t < TT; ++t) s += cs_part[(long)t * NBL + b];
        inv_cs[b] = 1.0f / s;
    }
}

// ---- K4: GEMM pass 2 — conf store + mconf zero + per-tile row/col max partials ----
__global__ __launch_bounds__(256) void gemm_pass2(
    const h16* __restrict__ A, const h16* __restrict__ B,
    const float* __restrict__ temp,
    const float* __restrict__ inv_rs, const float* __restrict__ inv_cs,
    float* __restrict__ conf, float* __restrict__ mconf,
    float* __restrict__ rm_part, float* __restrict__ cm_part)
{
    __shared__ __align__(16) h16 As[128 * 32];
    __shared__ __align__(16) h16 Bs[128 * 32];
    __shared__ float rp_lds[128][2];
    __shared__ float cp_lds[128][2];
    int bid = blockIdx.x;
    int n = bid / (TT * TT);
    int t = bid % (TT * TT);
    int tm = (t / TT) * 128;
    int tn = (t % TT) * 128;
    const h16* Ab = A + (long)n * L * CH;
    const h16* Bb = B + (long)n * L * CH;
    int tid = threadIdx.x;
    int lane = tid & 63;
    int w = tid >> 6;
    int wr = (w >> 1) * 64;
    int wc = (w & 1) * 64;

    f32x4 acc[4][4] = {};
    int lrow = lane >> 2;
    int kc8 = (lane & 3) * 8;

    for (int k0 = 0; k0 < CH; k0 += 32) {
        __syncthreads();
#pragma unroll
        for (int j = 0; j < 2; ++j) {
            int c = w * 2 + j;
            int row = c * 16 + lrow;
            int ga = tm + row; ga = ga > L - 1 ? L - 1 : ga;
            int gb = tn + row; gb = gb > L - 1 ? L - 1 : gb;
            __builtin_amdgcn_global_load_lds(
                (const __attribute__((address_space(1))) void*)(Ab + (long)ga * CH + k0 + kc8),
                (__attribute__((address_space(3))) void*)(As + c * 512), 16, 0, 0);
            __builtin_amdgcn_global_load_lds(
                (const __attribute__((address_space(1))) void*)(Bb + (long)gb * CH + k0 + kc8),
                (__attribute__((address_space(3))) void*)(Bs + c * 512), 16, 0, 0);
        }
        __syncthreads();

        h16x8 af[4], bf[4];
        int klo = (lane >> 4) * 8;
        int ra = wr + (lane & 15);
        int rb = wc + (lane & 15);
#pragma unroll
        for (int m = 0; m < 4; ++m) af[m] = *(const h16x8*)&As[(ra + m * 16) * 32 + klo];
#pragma unroll
        for (int nf = 0; nf < 4; ++nf) bf[nf] = *(const h16x8*)&Bs[(rb + nf * 16) * 32 + klo];
#pragma unroll
        for (int m = 0; m < 4; ++m)
#pragma unroll
            for (int nf = 0; nf < 4; ++nf)
                acc[m][nf] = __builtin_amdgcn_mfma_f32_16x16x32_f16(af[m], bf[nf], acc[m][nf], 0, 0, 0);
    }

    float scale = temp[0] * (1.0f / 256.0f);
    int row0 = tm + wr + ((lane >> 4) * 4);
    int col0 = tn + wc + (lane & 15);
    float ics[4];
#pragma unroll
    for (int nf = 0; nf < 4; ++nf) {
        int cc = col0 + nf * 16;
        ics[nf] = (cc < L) ? inv_cs[n * L + cc] : 0.f;
    }
    float cmax[4] = {0.f, 0.f, 0.f, 0.f};
#pragma unroll
    for (int m = 0; m < 4; ++m)
#pragma unroll
        for (int j = 0; j < 4; ++j) {
            int rr = row0 + m * 16 + j;
            float irs_v = (rr < L) ? inv_rs[n * L + rr] : 0.f;
            float rm = 0.f;
#pragma unroll
            for (int nf = 0; nf < 4; ++nf) {
                int cc = col0 + nf * 16;
                if (rr < L && cc < L) {
                    float e = __expf(acc[m][nf][j] * scale);
                    float c = (e * e) * irs_v * ics[nf];
                    conf[((long)n * L + rr) * L + cc] = c;
                    rm = fmaxf(rm, c);
                    cmax[nf] = fmaxf(cmax[nf], c);
                }
            }
            rm = fmaxf(rm, __shfl_xor(rm, 1)); rm = fmaxf(rm, __shfl_xor(rm, 2));
            rm = fmaxf(rm, __shfl_xor(rm, 4)); rm = fmaxf(rm, __shfl_xor(rm, 8));
            if ((lane & 15) == 0)
                rp_lds[wr + (lane >> 4) * 4 + m * 16 + j][w & 1] = rm;
        }
#pragma unroll
    for (int nf = 0; nf < 4; ++nf) {
        float v = cmax[nf];
        v = fmaxf(v, __shfl_xor(v, 16)); v = fmaxf(v, __shfl_xor(v, 32));
        if (lane < 16)
            cp_lds[wc + lane + nf * 16][w >> 1] = v;
    }
    __syncthreads();
    if (tid < 128) {
        int rr = tm + tid;
        if (rr < L)
            rm_part[(long)(t % TT) * NBL + n * L + rr] = fmaxf(rp_lds[tid][0], rp_lds[tid][1]);
    } else {
        int c2 = tid - 128;
        int cc = tn + c2;
        if (cc < L)
            cm_part[(long)(t / TT) * NBL + n * L + cc] = fmaxf(cp_lds[c2][0], cp_lds[c2][1]);
    }

    // zero this tile's region of mconf (coalesced f32x4)
    f32x4 z = {0.f, 0.f, 0.f, 0.f};
    for (int i = tid; i < 128 * 32; i += 256) {
        int r = i >> 5;
        int cv = (i & 31) * 4;
        int rr = tm + r, cc = tn + cv;
        if (rr < L && cc + 3 < L)
            *(f32x4*)&mconf[((long)n * L + rr) * L + cc] = z;
    }
}

// ---- K5: fixed-order reduce of max partials ----
__global__ __launch_bounds__(256) void reduce_max(
    const float* __restrict__ rm_part, const float* __restrict__ cm_part,
    float* __restrict__ rowmaxf, float* __restrict__ colmaxf)
{
    int i = blockIdx.x * 256 + threadIdx.x;
    if (i < NBL) {
        float m = 0.f;
        for (int t = 0; t < TT; ++t) m = fmaxf(m, rm_part[(long)t * NBL + i]);
        rowmaxf[i] = m;
    } else if (i < 2 * NBL) {
        int b = i - NBL;
        float m = 0.f;
        for (int t = 0; t < TT; ++t) m = fmaxf(m, cm_part[(long)t * NBL + b]);
        colmaxf[b] = m;
    }
}

// ---- K6: per-row match scan (early-out when row can't match) ----
__global__ __launch_bounds__(256) void mconf_rows(
    const float* __restrict__ conf, const float* __restrict__ rowmaxf,
    const float* __restrict__ colmaxf, float* __restrict__ mconf)
{
    int b = blockIdx.x;                 // n*L + l
    float rmax = rowmaxf[b];
    if (!(rmax > THRF)) return;         // no element in row exceeds threshold
    int l = b % L;
    int h0 = l / 80, w0 = l % 80;
    if (!((h0 >= 2) && (h0 < 58) && (w0 >= 2) && (w0 < 78))) return;
    int n = b / L;
    const float* Crow = conf + (long)b * L;
    for (int s = threadIdx.x; s < L; s += 256) {
        float c = Crow[s];
        if (c > THRF && c == rmax && c == colmaxf[n * L + s]) {
            int h1 = s / 80, w1 = s % 80;
            if ((h1 >= 2) && (h1 < 58) && (w1 >= 2) && (w1 < 78))
                mconf[(long)b * L + s] = c;
        }
    }
}

extern "C" void kernel_launch(void* const* d_in, const int* in_sizes, int n_in,
                              void* d_out, int out_size, void* d_ws, size_t ws_size,
                              hipStream_t stream)
{
    const float* f0 = (const float*)d_in[0];
    const float* f1 = (const float*)d_in[1];
    const float* temp = (const float*)d_in[2];

    float* conf  = (float*)d_out;
    float* mconf = conf + (long)NB * L * L;   // second half of d_out

    // d_ws layout (deterministic, no atomics, no counters):
    float* inv_rs  = (float*)d_ws;                         // NBL
    float* inv_cs  = inv_rs + NBL;                         // NBL
    float* rowmaxf = inv_cs + NBL;                         // NBL
    float* colmaxf = rowmaxf + NBL;                        // NBL
    float* rs_part = colmaxf + NBL;                        // TT*NBL
    float* cs_part = rs_part + (long)TT * NBL;             // TT*NBL
    float* rm_part = cs_part + (long)TT * NBL;             // TT*NBL
    float* cm_part = rm_part + (long)TT * NBL;             // TT*NBL
    h16*   Abf     = (h16*)(cm_part + (long)TT * NBL);     // NB*L*CH fp16
    h16*   Bbf     = Abf + (long)NB * L * CH;

    convert_kernel<<<(NB * L * CH / 4 + 255) / 256, 256, 0, stream>>>(f0, f1, Abf, Bbf);
    gemm_pass1<<<NB * TT * TT, 256, 0, stream>>>(Abf, Bbf, temp, rs_part, cs_part);
    reduce_inv<<<(2 * NBL + 255) / 256, 256, 0, stream>>>(rs_part, cs_part, inv_rs, inv_cs);
    gemm_pass2<<<NB * TT * TT, 256, 0, stream>>>(Abf, Bbf, temp, inv_rs, inv_cs,
                                                 conf, mconf, rm_part, cm_part);
    reduce_max<<<(2 * NBL + 255) / 256, 256, 0, stream>>>(rm_part, cm_part, rowmaxf, colmaxf);
    mconf_rows<<<NBL, 256, 0, stream>>>(conf, rowmaxf, colmaxf, mconf);
}

// Round 7
// 469.832 us; speedup vs baseline: 1.3386x; 1.0115x over previous
//
#include <hip/hip_runtime.h>

#define L 4800
#define CH 256
#define NB 2
#define TT 38              // ceil(4800/128)
#define NBL (NB * L)       // 9600
#define THRF 0.2f

typedef float f32x4 __attribute__((ext_vector_type(4)));
typedef _Float16 h16;
typedef _Float16 h16x4 __attribute__((ext_vector_type(4)));
typedef _Float16 h16x8 __attribute__((ext_vector_type(8)));

// ---- K1: fp32 -> fp16 convert (elementwise) ----
__global__ __launch_bounds__(256) void convert_kernel(
    const float* __restrict__ f0, const float* __restrict__ f1,
    h16* __restrict__ A, h16* __restrict__ B)
{
    int idx = blockIdx.x * 256 + threadIdx.x;
    if (idx >= NB * L * CH / 4) return;
    f32x4 a = ((const f32x4*)f0)[idx];
    f32x4 b = ((const f32x4*)f1)[idx];
    h16x4 ah, bh;
#pragma unroll
    for (int k = 0; k < 4; ++k) { ah[k] = (h16)a[k]; bh[k] = (h16)b[k]; }
    ((h16x4*)A)[idx] = ah;
    ((h16x4*)B)[idx] = bh;
}

// ---- K2: GEMM pass 1 — per-tile row/col sums of exp(sim) + mconf zero-fill ----
// MFMA operands swapped: lane holds (row = lane&15, 4 consecutive cols).
__global__ __launch_bounds__(256) void gemm_pass1(
    const h16* __restrict__ A, const h16* __restrict__ B,
    const float* __restrict__ temp,
    float* __restrict__ rs_part, float* __restrict__ cs_part,
    float* __restrict__ mconf)
{
    __shared__ __align__(16) h16 As[128 * 32];
    __shared__ __align__(16) h16 Bs[128 * 32];
    __shared__ float rp_lds[128][2];
    __shared__ float cp_lds[128][2];
    int bid = blockIdx.x;
    int n = bid / (TT * TT);
    int t = bid % (TT * TT);
    int tm = (t / TT) * 128;
    int tn = (t % TT) * 128;
    const h16* Ab = A + (long)n * L * CH;
    const h16* Bb = B + (long)n * L * CH;
    int tid = threadIdx.x;
    int lane = tid & 63;
    int w = tid >> 6;
    int wr = (w >> 1) * 64;
    int wc = (w & 1) * 64;

    f32x4 acc[4][4] = {};
    int lrow = lane >> 2;
    int kc8 = (lane & 3) * 8;

    for (int k0 = 0; k0 < CH; k0 += 32) {
        __syncthreads();
#pragma unroll
        for (int j = 0; j < 2; ++j) {
            int c = w * 2 + j;
            int row = c * 16 + lrow;
            int ga = tm + row; ga = ga > L - 1 ? L - 1 : ga;
            int gb = tn + row; gb = gb > L - 1 ? L - 1 : gb;
            __builtin_amdgcn_global_load_lds(
                (const __attribute__((address_space(1))) void*)(Ab + (long)ga * CH + k0 + kc8),
                (__attribute__((address_space(3))) void*)(As + c * 512), 16, 0, 0);
            __builtin_amdgcn_global_load_lds(
                (const __attribute__((address_space(1))) void*)(Bb + (long)gb * CH + k0 + kc8),
                (__attribute__((address_space(3))) void*)(Bs + c * 512), 16, 0, 0);
        }
        __syncthreads();

        h16x8 af[4], bf[4];
        int klo = (lane >> 4) * 8;
        int ra = wr + (lane & 15);
        int rb = wc + (lane & 15);
#pragma unroll
        for (int m = 0; m < 4; ++m) af[m] = *(const h16x8*)&As[(ra + m * 16) * 32 + klo];
#pragma unroll
        for (int nf = 0; nf < 4; ++nf) bf[nf] = *(const h16x8*)&Bs[(rb + nf * 16) * 32 + klo];
        // swapped operands: acc[m][nf] has row = lane&15 (A-row), cols = (lane>>4)*4+j (B-rows)
#pragma unroll
        for (int m = 0; m < 4; ++m)
#pragma unroll
            for (int nf = 0; nf < 4; ++nf)
                acc[m][nf] = __builtin_amdgcn_mfma_f32_16x16x32_f16(bf[nf], af[m], acc[m][nf], 0, 0, 0);
    }

    float scale = temp[0] * (1.0f / 256.0f);
    int lr = lane & 15;
    int lc4 = (lane >> 4) * 4;
    float rowp[4] = {0.f, 0.f, 0.f, 0.f};
    f32x4 colp[4] = {};
#pragma unroll
    for (int m = 0; m < 4; ++m) {
        int rr = tm + wr + m * 16 + lr;
#pragma unroll
        for (int nf = 0; nf < 4; ++nf) {
            int ccb = tn + wc + nf * 16 + lc4;
#pragma unroll
            for (int j = 0; j < 4; ++j) {
                float e = 0.f;
                if (rr < L && (ccb + j) < L) e = __expf(acc[m][nf][j] * scale);
                rowp[m] += e;
                colp[nf][j] += e;
            }
        }
    }
    // row partials: reduce across lanes sharing (lane&15)
#pragma unroll
    for (int m = 0; m < 4; ++m) {
        float v = rowp[m];
        v += __shfl_xor(v, 16); v += __shfl_xor(v, 32);
        if (lane < 16) rp_lds[wr + m * 16 + lr][w & 1] = v;
    }
    // col partials: reduce across the 16-lane row groups
#pragma unroll
    for (int nf = 0; nf < 4; ++nf)
#pragma unroll
        for (int j = 0; j < 4; ++j) {
            float v = colp[nf][j];
            v += __shfl_xor(v, 1); v += __shfl_xor(v, 2);
            v += __shfl_xor(v, 4); v += __shfl_xor(v, 8);
            if ((lane & 15) == 0) cp_lds[wc + nf * 16 + lc4 + j][w >> 1] = v;
        }
    __syncthreads();
    if (tid < 128) {
        int rr = tm + tid;
        if (rr < L)
            rs_part[(long)(t % TT) * NBL + n * L + rr] = rp_lds[tid][0] + rp_lds[tid][1];
    } else {
        int c2 = tid - 128;
        int cc = tn + c2;
        if (cc < L)
            cs_part[(long)(t / TT) * NBL + n * L + cc] = cp_lds[c2][0] + cp_lds[c2][1];
    }

    // zero this tile's region of mconf (overlaps with other blocks' compute)
    f32x4 z = {0.f, 0.f, 0.f, 0.f};
    for (int i = tid; i < 128 * 32; i += 256) {
        int r = i >> 5;
        int cv = (i & 31) * 4;
        int rr = tm + r, cc = tn + cv;
        if (rr < L && cc < L)
            *(f32x4*)&mconf[((long)n * L + rr) * L + cc] = z;
    }
}

// ---- K3: fixed-order reduce of partials -> reciprocals ----
__global__ __launch_bounds__(256) void reduce_inv(
    const float* __restrict__ rs_part, const float* __restrict__ cs_part,
    float* __restrict__ inv_rs, float* __restrict__ inv_cs)
{
    int i = blockIdx.x * 256 + threadIdx.x;
    if (i < NBL) {
        float s = 0.f;
        for (int t = 0; t < TT; ++t) s += rs_part[(long)t * NBL + i];
        inv_rs[i] = 1.0f / s;
    } else if (i < 2 * NBL) {
        int b = i - NBL;
        float s = 0.f;
        for (int t = 0; t < TT; ++t) s += cs_part[(long)t * NBL + b];
        inv_cs[b] = 1.0f / s;
    }
}

// ---- K4: GEMM pass 2 — vectorized conf store + per-tile row/col max partials ----
__global__ __launch_bounds__(256) void gemm_pass2(
    const h16* __restrict__ A, const h16* __restrict__ B,
    const float* __restrict__ temp,
    const float* __restrict__ inv_rs, const float* __restrict__ inv_cs,
    float* __restrict__ conf,
    float* __restrict__ rm_part, float* __restrict__ cm_part)
{
    __shared__ __align__(16) h16 As[128 * 32];
    __shared__ __align__(16) h16 Bs[128 * 32];
    __shared__ float rp_lds[128][2];
    __shared__ float cp_lds[128][2];
    int bid = blockIdx.x;
    int n = bid / (TT * TT);
    int t = bid % (TT * TT);
    int tm = (t / TT) * 128;
    int tn = (t % TT) * 128;
    const h16* Ab = A + (long)n * L * CH;
    const h16* Bb = B + (long)n * L * CH;
    int tid = threadIdx.x;
    int lane = tid & 63;
    int w = tid >> 6;
    int wr = (w >> 1) * 64;
    int wc = (w & 1) * 64;

    f32x4 acc[4][4] = {};
    int lrow = lane >> 2;
    int kc8 = (lane & 3) * 8;

    for (int k0 = 0; k0 < CH; k0 += 32) {
        __syncthreads();
#pragma unroll
        for (int j = 0; j < 2; ++j) {
            int c = w * 2 + j;
            int row = c * 16 + lrow;
            int ga = tm + row; ga = ga > L - 1 ? L - 1 : ga;
            int gb = tn + row; gb = gb > L - 1 ? L - 1 : gb;
            __builtin_amdgcn_global_load_lds(
                (const __attribute__((address_space(1))) void*)(Ab + (long)ga * CH + k0 + kc8),
                (__attribute__((address_space(3))) void*)(As + c * 512), 16, 0, 0);
            __builtin_amdgcn_global_load_lds(
                (const __attribute__((address_space(1))) void*)(Bb + (long)gb * CH + k0 + kc8),
                (__attribute__((address_space(3))) void*)(Bs + c * 512), 16, 0, 0);
        }
        __syncthreads();

        h16x8 af[4], bf[4];
        int klo = (lane >> 4) * 8;
        int ra = wr + (lane & 15);
        int rb = wc + (lane & 15);
#pragma unroll
        for (int m = 0; m < 4; ++m) af[m] = *(const h16x8*)&As[(ra + m * 16) * 32 + klo];
#pragma unroll
        for (int nf = 0; nf < 4; ++nf) bf[nf] = *(const h16x8*)&Bs[(rb + nf * 16) * 32 + klo];
#pragma unroll
        for (int m = 0; m < 4; ++m)
#pragma unroll
            for (int nf = 0; nf < 4; ++nf)
                acc[m][nf] = __builtin_amdgcn_mfma_f32_16x16x32_f16(bf[nf], af[m], acc[m][nf], 0, 0, 0);
    }

    // epilogue: conf = (e*e)*irs*ics computed once; f32x4 row-major stores
    float scale = temp[0] * (1.0f / 256.0f);
    int lr = lane & 15;
    int lc4 = (lane >> 4) * 4;
    f32x4 ics4[4];
#pragma unroll
    for (int nf = 0; nf < 4; ++nf) {
        int ccb = tn + wc + nf * 16 + lc4;
        if (ccb < L) ics4[nf] = *(const f32x4*)&inv_cs[n * L + ccb];
        else { ics4[nf][0] = 0.f; ics4[nf][1] = 0.f; ics4[nf][2] = 0.f; ics4[nf][3] = 0.f; }
    }
    float rowm[4] = {0.f, 0.f, 0.f, 0.f};
    f32x4 colm[4] = {};
#pragma unroll
    for (int m = 0; m < 4; ++m) {
        int rr = tm + wr + m * 16 + lr;
        float irs_v = (rr < L) ? inv_rs[n * L + rr] : 0.f;
#pragma unroll
        for (int nf = 0; nf < 4; ++nf) {
            int ccb = tn + wc + nf * 16 + lc4;
            f32x4 cv;
#pragma unroll
            for (int j = 0; j < 4; ++j) {
                float e = __expf(acc[m][nf][j] * scale);
                float c = (e * e) * irs_v * ics4[nf][j];   // 0 when rr/cc OOB
                cv[j] = c;
                rowm[m] = fmaxf(rowm[m], c);
                colm[nf][j] = fmaxf(colm[nf][j], c);
            }
            if (rr < L && ccb < L)
                *(f32x4*)&conf[((long)n * L + rr) * L + ccb] = cv;
        }
    }
#pragma unroll
    for (int m = 0; m < 4; ++m) {
        float v = rowm[m];
        v = fmaxf(v, __shfl_xor(v, 16)); v = fmaxf(v, __shfl_xor(v, 32));
        if (lane < 16) rp_lds[wr + m * 16 + lr][w & 1] = v;
    }
#pragma unroll
    for (int nf = 0; nf < 4; ++nf)
#pragma unroll
        for (int j = 0; j < 4; ++j) {
            float v = colm[nf][j];
            v = fmaxf(v, __shfl_xor(v, 1)); v = fmaxf(v, __shfl_xor(v, 2));
            v = fmaxf(v, __shfl_xor(v, 4)); v = fmaxf(v, __shfl_xor(v, 8));
            if ((lane & 15) == 0) cp_lds[wc + nf * 16 + lc4 + j][w >> 1] = v;
        }
    __syncthreads();
    if (tid < 128) {
        int rr = tm + tid;
        if (rr < L)
            rm_part[(long)(t % TT) * NBL + n * L + rr] = fmaxf(rp_lds[tid][0], rp_lds[tid][1]);
    } else {
        int c2 = tid - 128;
        int cc = tn + c2;
        if (cc < L)
            cm_part[(long)(t / TT) * NBL + n * L + cc] = fmaxf(cp_lds[c2][0], cp_lds[c2][1]);
    }
}

// ---- K5: fixed-order reduce of max partials ----
__global__ __launch_bounds__(256) void reduce_max(
    const float* __restrict__ rm_part, const float* __restrict__ cm_part,
    float* __restrict__ rowmaxf, float* __restrict__ colmaxf)
{
    int i = blockIdx.x * 256 + threadIdx.x;
    if (i < NBL) {
        float m = 0.f;
        for (int t = 0; t < TT; ++t) m = fmaxf(m, rm_part[(long)t * NBL + i]);
        rowmaxf[i] = m;
    } else if (i < 2 * NBL) {
        int b = i - NBL;
        float m = 0.f;
        for (int t = 0; t < TT; ++t) m = fmaxf(m, cm_part[(long)t * NBL + b]);
        colmaxf[b] = m;
    }
}

// ---- K6: per-row match scan (early-out when row can't match) ----
__global__ __launch_bounds__(256) void mconf_rows(
    const float* __restrict__ conf, const float* __restrict__ rowmaxf,
    const float* __restrict__ colmaxf, float* __restrict__ mconf)
{
    int b = blockIdx.x;                 // n*L + l
    float rmax = rowmaxf[b];
    if (!(rmax > THRF)) return;         // no element in row exceeds threshold
    int l = b % L;
    int h0 = l / 80, w0 = l % 80;
    if (!((h0 >= 2) && (h0 < 58) && (w0 >= 2) && (w0 < 78))) return;
    int n = b / L;
    const float* Crow = conf + (long)b * L;
    for (int s = threadIdx.x; s < L; s += 256) {
        float c = Crow[s];
        if (c > THRF && c == rmax && c == colmaxf[n * L + s]) {
            int h1 = s / 80, w1 = s % 80;
            if ((h1 >= 2) && (h1 < 58) && (w1 >= 2) && (w1 < 78))
                mconf[(long)b * L + s] = c;
        }
    }
}

extern "C" void kernel_launch(void* const* d_in, const int* in_sizes, int n_in,
                              void* d_out, int out_size, void* d_ws, size_t ws_size,
                              hipStream_t stream)
{
    const float* f0 = (const float*)d_in[0];
    const float* f1 = (const float*)d_in[1];
    const float* temp = (const float*)d_in[2];

    float* conf  = (float*)d_out;
    float* mconf = conf + (long)NB * L * L;   // second half of d_out

    // d_ws layout (deterministic, no atomics, no counters):
    float* inv_rs  = (float*)d_ws;                         // NBL
    float* inv_cs  = inv_rs + NBL;                         // NBL
    float* rowmaxf = inv_cs + NBL;                         // NBL
    float* colmaxf = rowmaxf + NBL;                        // NBL
    float* rs_part = colmaxf + NBL;                        // TT*NBL
    float* cs_part = rs_part + (long)TT * NBL;             // TT*NBL
    float* rm_part = cs_part + (long)TT * NBL;             // TT*NBL
    float* cm_part = rm_part + (long)TT * NBL;             // TT*NBL
    h16*   Abf     = (h16*)(cm_part + (long)TT * NBL);     // NB*L*CH fp16
    h16*   Bbf     = Abf + (long)NB * L * CH;

    convert_kernel<<<(NB * L * CH / 4 + 255) / 256, 256, 0, stream>>>(f0, f1, Abf, Bbf);
    gemm_pass1<<<NB * TT * TT, 256, 0, stream>>>(Abf, Bbf, temp, rs_part, cs_part, mconf);
    reduce_inv<<<(2 * NBL + 255) / 256, 256, 0, stream>>>(rs_part, cs_part, inv_rs, inv_cs);
    gemm_pass2<<<NB * TT * TT, 256, 0, stream>>>(Abf, Bbf, temp, inv_rs, inv_cs,
                                                 conf, rm_part, cm_part);
    reduce_max<<<(2 * NBL + 255) / 256, 256, 0, stream>>>(rm_part, cm_part, rowmaxf, colmaxf);
    mconf_rows<<<NBL, 256, 0, stream>>>(conf, rowmaxf, colmaxf, mconf);
}